// Round 12
// baseline (799.842 us; speedup 1.0000x reference)
//
#include <hip/hip_runtime.h>
#include <hip/hip_bf16.h>

// Problem constants (fixed by the reference)
#define NN   507904          // nodes = 8192*62
#define NE   4063232         // edges = NN*8
#define NG   8192            // graphs
#define NPG  62              // nodes per graph
#define NBLKM 1984           // NN/256 (mlp grid; 256 rows/block, 4 iters)

// Bucket sort parameters
#define NB    248            // buckets = NN/2048 (exact)
#define BRNG  2048           // nodes per bucket (bucket = dst>>11)
#define BCAP  17152          // bucket record capacity (mean 16384, +6 sigma)
#define PBCAP 31744          // padded csr capacity/bucket (8-aligned)
#define P3BLK 992            // NE/4096 (exact)
#define CSRSZ (NB * PBCAP)   // 7,872,512 ints

// ---------------------------------------------------------------- ws layout (4B units)
#define OFF_R     0                          // NN*64 units; bf16 rows (+sentinel) or fp32 L3 out
#define OFF_AGGBF (OFF_R + NN * 64)          // t: bf16 NN*64 | aliased: RECS / T1
#define OFF_CSR   (OFF_AGGBF + NN * 32)      // CSRSZ ints (padded CSR)
#define OFF_CNT   (OFF_CSR + CSRSZ)          // NN ints
#define OFF_OFFA  (OFF_CNT + NN)             // NN ints
#define OFF_BCUR  (OFF_OFFA + NN)            // 256 ints
#define OFF_PART  (OFF_BCUR + 256)           // NBLKM*128 floats
#define OFF_TOT   (OFF_PART + NBLKM * 128)   // 128 doubles = 256 units
#define OFF_WTB   (OFF_TOT + 256)            // bf16 weights: 22528 ushort = 11264 units
#define OFF_SS    (OFF_WTB + 11264)          // 3 x (scale[64], shift[64])

// bf16 weight offsets (ushort units)
#define WB_W1B 0
#define WB_W2A 4096
#define WB_W2B 8192
#define WB_W3A 12288
#define WB_W3B 16384
#define WB_W1A 20480         // 64 x 32, zero-padded K (only k<4 nonzero)

typedef __attribute__((ext_vector_type(8))) short short8;
typedef __attribute__((ext_vector_type(4))) float f32x4;
typedef unsigned short ushort_t;

__device__ __forceinline__ ushort_t f2bf_bits(float f) {
  union { float f; unsigned u; } x; x.f = f;
  unsigned r = x.u + 0x7FFF + ((x.u >> 16) & 1);
  return (ushort_t)(r >> 16);
}
__device__ __forceinline__ float bf_lo(unsigned u) {
  union { unsigned i; float f; } x; x.i = u << 16; return x.f;
}
__device__ __forceinline__ float bf_hi(unsigned u) {
  union { unsigned i; float f; } x; x.i = u & 0xFFFF0000u; return x.f;
}

// ---------------------------------------------------------------- weight prep
__global__ __launch_bounds__(256) void prep_weights(
    const float* __restrict__ w1a, const float* __restrict__ w1b,
    const float* __restrict__ w2a, const float* __restrict__ w2b,
    const float* __restrict__ w3a, const float* __restrict__ w3b,
    ushort_t* __restrict__ wtb) {
  int b = blockIdx.x, tid = threadIdx.x;
  if (b == 0) {
    // W1a [4][64] -> bf16 [n][32], zero-padded K (k<4 nonzero)
    ushort_t* d = wtb + WB_W1A;
    for (int i = tid; i < 2048; i += 256) {
      int n = i >> 5, k = i & 31;
      d[i] = (k < 4) ? f2bf_bits(w1a[k * 64 + n]) : (ushort_t)0;
    }
  } else {
    const float* s; ushort_t* d;
    switch (b) {
      case 1: s = w1b; d = wtb + WB_W1B; break;
      case 2: s = w2a; d = wtb + WB_W2A; break;
      case 3: s = w2b; d = wtb + WB_W2B; break;
      case 4: s = w3a; d = wtb + WB_W3A; break;
      default: s = w3b; d = wtb + WB_W3B; break;
    }
    for (int i = tid; i < 4096; i += 256) {
      int k = i >> 6, n = i & 63;              // src [k][n]
      d[n * 64 + k] = f2bf_bits(s[i]);         // dst [n][k]
    }
  }
}

// ---------------------------------------------------------------- CSR build: phase 1 (R6-proven)
__global__ __launch_bounds__(256) void p3_bin(
    const int* __restrict__ src, const int* __restrict__ dst,
    int* __restrict__ bcur, uint2* __restrict__ recs) {
  __shared__ int histo[256];
  __shared__ int scan_s[256];
  __shared__ int base_s[256];
  __shared__ int cur_s[256];
  __shared__ uint2 buf[4096];
  const int tid = threadIdx.x;
  const int e0 = blockIdx.x * 4096;

  histo[tid] = 0;
  __syncthreads();

  int d_[16], s_[16];
#pragma unroll
  for (int k = 0; k < 16; ++k) {
    int e = e0 + k * 256 + tid;
    d_[k] = dst[e]; s_[k] = src[e];
    atomicAdd(&histo[d_[k] >> 11], 1);
  }
  __syncthreads();

  int v = histo[tid];
  scan_s[tid] = v; __syncthreads();
  for (int s = 1; s < 256; s <<= 1) {
    int add = (tid >= s) ? scan_s[tid - s] : 0;
    __syncthreads();
    scan_s[tid] += add;
    __syncthreads();
  }
  int excl = scan_s[tid] - v;
  if (tid < NB) base_s[tid] = atomicAdd(&bcur[tid], v);
  cur_s[tid] = excl;
  histo[tid] = excl;
  __syncthreads();

#pragma unroll
  for (int k = 0; k < 16; ++k) {
    int b = d_[k] >> 11;
    int p = atomicAdd(&cur_s[b], 1);
    uint2 r; r.x = (unsigned)d_[k]; r.y = (unsigned)s_[k];
    buf[p] = r;
  }
  __syncthreads();

  for (int i = tid; i < 4096; i += 256) {
    uint2 r = buf[i];
    int b = (int)(r.x >> 11);
    int g = base_s[b] + (i - histo[b]);
    if (g < BCAP) recs[(size_t)b * BCAP + g] = r;
  }
}

// ---------------------------------------------------------------- CSR build: phase 2 (R6-proven, LDS cursors)
__global__ __launch_bounds__(1024) void p4_build(
    const uint2* __restrict__ recs, const int* __restrict__ bcur,
    int* __restrict__ csr, int* __restrict__ cnt, int* __restrict__ offa) {
  __shared__ int lcnt[2048];
  __shared__ int pscan[1024];
  __shared__ int sstart[2048];
  __shared__ int scur[2048];
  const int b = blockIdx.x, tid = threadIdx.x;
  int m = bcur[b]; if (m > BCAP) m = BCAP;
  const int cbase = b * PBCAP;
  const int nbase = b << 11;
  const uint2* rp = recs + (size_t)b * BCAP;

  lcnt[tid] = 0; lcnt[1024 + tid] = 0;
  __syncthreads();
  for (int i = tid; i < m; i += 1024)
    atomicAdd(&lcnt[rp[i].x & (BRNG - 1)], 1);
  __syncthreads();

  int a0 = lcnt[2 * tid], a1 = lcnt[2 * tid + 1];
  int p0 = (a0 + 7) & ~7, p1 = (a1 + 7) & ~7;
  int ps = p0 + p1;
  pscan[tid] = ps; __syncthreads();
  for (int s = 1; s < 1024; s <<= 1) {
    int add = (tid >= s) ? pscan[tid - s] : 0;
    __syncthreads();
    pscan[tid] += add;
    __syncthreads();
  }
  int e0 = pscan[tid] - ps;
  sstart[2 * tid] = e0;          scur[2 * tid] = e0;
  sstart[2 * tid + 1] = e0 + p0; scur[2 * tid + 1] = e0 + p0;
  __syncthreads();

  cnt[nbase + tid] = lcnt[tid];
  cnt[nbase + 1024 + tid] = lcnt[1024 + tid];
  offa[nbase + tid] = cbase + sstart[tid];
  offa[nbase + 1024 + tid] = cbase + sstart[1024 + tid];
  __syncthreads();

  for (int i = tid; i < m; i += 1024) {
    uint2 r = rp[i];
    int p = atomicAdd(&scur[r.x & (BRNG - 1)], 1);
    csr[cbase + p] = (int)r.y;
  }
  __syncthreads();

#pragma unroll
  for (int k = 0; k < 2; ++k) {
    int i = k * 1024 + tid;
    int st = sstart[i], d = lcnt[i], p = (d + 7) & ~7;
    for (int q = d; q < p; ++q) csr[cbase + st + q] = NN;   // sentinel
  }
}

// ---------------------------------------------------------------- gather L1 (C=4)
__global__ __launch_bounds__(256) void gather1(
    const float4* __restrict__ x, const int* __restrict__ csr,
    const int* __restrict__ offa, const int* __restrict__ cnt,
    float4* __restrict__ tout) {
  int n = blockIdx.x * 256 + threadIdx.x;
  float4 a = x[n];
  int off = offa[n], deg = cnt[n];
  const int* cp = csr + off;
  int j = 0;
  for (; j + 4 <= deg; j += 4) {
    int s0 = cp[j], s1 = cp[j + 1], s2 = cp[j + 2], s3 = cp[j + 3];
    float4 v0 = x[s0], v1 = x[s1], v2 = x[s2], v3 = x[s3];
    a.x += v0.x + v1.x + v2.x + v3.x;
    a.y += v0.y + v1.y + v2.y + v3.y;
    a.z += v0.z + v1.z + v2.z + v3.z;
    a.w += v0.w + v1.w + v2.w + v3.w;
  }
  for (; j < deg; ++j) {
    float4 v = x[cp[j]];
    a.x += v.x; a.y += v.y; a.z += v.z; a.w += v.w;
  }
  tout[n] = a;
}

// ---------------------------------------------------------------- gather L2/3 (C=64, bf16 rows)
__global__ __launch_bounds__(256) void gather64v2(
    const ushort_t* __restrict__ h, const int* __restrict__ csr,
    const int* __restrict__ offa, const int* __restrict__ cnt,
    const float* __restrict__ ss, ushort_t* __restrict__ tout) {
  const int lane = threadIdx.x & 63;
  const int n = blockIdx.x * 4 + (threadIdx.x >> 6);
  const int g = lane >> 3, sub = lane & 7;
  const int deg = cnt[n];
  const int off = offa[n];
  const int chunks = (deg + 7) >> 3;

  float acc[8] = {0.f, 0.f, 0.f, 0.f, 0.f, 0.f, 0.f, 0.f};
  for (int c = 0; c < chunks; ++c) {
    int row = csr[off + (c << 3) + g];
    uint4 u = *(const uint4*)(h + (size_t)row * 64 + (sub << 3));
    acc[0] += bf_lo(u.x); acc[1] += bf_hi(u.x);
    acc[2] += bf_lo(u.y); acc[3] += bf_hi(u.y);
    acc[4] += bf_lo(u.z); acc[5] += bf_hi(u.z);
    acc[6] += bf_lo(u.w); acc[7] += bf_hi(u.w);
  }
#pragma unroll
  for (int j = 0; j < 8; ++j) {
    acc[j] += __shfl_xor(acc[j], 8);
    acc[j] += __shfl_xor(acc[j], 16);
    acc[j] += __shfl_xor(acc[j], 32);
  }

  if (g == 0) {
    uint4 u = *(const uint4*)(h + (size_t)n * 64 + (sub << 3));
    acc[0] += bf_lo(u.x); acc[1] += bf_hi(u.x);
    acc[2] += bf_lo(u.y); acc[3] += bf_hi(u.y);
    acc[4] += bf_lo(u.z); acc[5] += bf_hi(u.z);
    acc[6] += bf_lo(u.w); acc[7] += bf_hi(u.w);
    const float m1 = (float)(deg + 1);
    const float4* scp = (const float4*)(ss + (sub << 3));
    const float4* sfp = (const float4*)(ss + 64 + (sub << 3));
    float4 sc0 = scp[0], sc1 = scp[1];
    float4 sf0 = sfp[0], sf1 = sfp[1];
    float t0 = fmaf(sc0.x, acc[0], m1 * sf0.x);
    float t1 = fmaf(sc0.y, acc[1], m1 * sf0.y);
    float t2 = fmaf(sc0.z, acc[2], m1 * sf0.z);
    float t3 = fmaf(sc0.w, acc[3], m1 * sf0.w);
    float t4 = fmaf(sc1.x, acc[4], m1 * sf1.x);
    float t5 = fmaf(sc1.y, acc[5], m1 * sf1.y);
    float t6 = fmaf(sc1.z, acc[6], m1 * sf1.z);
    float t7 = fmaf(sc1.w, acc[7], m1 * sf1.w);
    uint4 o;
    o.x = ((unsigned)f2bf_bits(t1) << 16) | f2bf_bits(t0);
    o.y = ((unsigned)f2bf_bits(t3) << 16) | f2bf_bits(t2);
    o.z = ((unsigned)f2bf_bits(t5) << 16) | f2bf_bits(t4);
    o.w = ((unsigned)f2bf_bits(t7) << 16) | f2bf_bits(t6);
    *(uint4*)(tout + (size_t)n * 64 + (sub << 3)) = o;
  }
}

// ---------------------------------------------------------------- MFMA MLP (unified L1/L2/L3)
// 256 rows/block, 4 iters; grid 1984 (7.75 blocks/CU for better balance).
template <bool L1, bool BFOUT>
__global__ __launch_bounds__(256) void mlp_mfma(
    const void* __restrict__ tin,
    const ushort_t* __restrict__ WaTb,   // L1: bf16 [n][32] padded; else [n][64]
    const float* __restrict__ ba,
    const ushort_t* __restrict__ WbTb,   // bf16 [n][64]
    const float* __restrict__ bb,
    float* __restrict__ routf, ushort_t* __restrict__ routb,
    float* __restrict__ part) {
  __shared__ __align__(16) ushort_t zt[4096];
  __shared__ float red[512];
  const int tid = threadIdx.x;
  const int wave = tid >> 6, lane = tid & 63;
  const int col = lane & 15, quad = lane >> 4;

  short8 bWa1[4];        // L1 only
  short8 bWa[2][4];      // !L1 only
  short8 bWb[2][4];
#pragma unroll
  for (int nt = 0; nt < 4; ++nt) {
    if (L1) {
      bWa1[nt] = *(const short8*)(WaTb + (nt * 16 + col) * 32 + quad * 8);
    } else {
#pragma unroll
      for (int k0 = 0; k0 < 2; ++k0)
        bWa[k0][nt] = *(const short8*)(WaTb + (nt * 16 + col) * 64 + k0 * 32 + quad * 8);
    }
#pragma unroll
    for (int k0 = 0; k0 < 2; ++k0)
      bWb[k0][nt] = *(const short8*)(WbTb + (nt * 16 + col) * 64 + k0 * 32 + quad * 8);
  }
  float ba_n[4], bb_n[4];
#pragma unroll
  for (int nt = 0; nt < 4; ++nt) {
    ba_n[nt] = ba[nt * 16 + col];
    bb_n[nt] = bb[nt * 16 + col];
  }

  const int wbase = wave * 1024;
  float scol[4] = {0, 0, 0, 0}, qcol[4] = {0, 0, 0, 0};

  for (int it = 0; it < 4; ++it) {
    const int tile = blockIdx.x * 256 + it * 64 + wave * 16;

    f32x4 acc1[4];
#pragma unroll
    for (int nt = 0; nt < 4; ++nt) acc1[nt] = (f32x4){0.f, 0.f, 0.f, 0.f};

    if constexpr (L1) {
      // A-frag: m=col, k=quad*8+j; real data only k<4
      float4 t4 = ((const float4*)tin)[tile + col];
      short8 az = {0, 0, 0, 0, 0, 0, 0, 0};
      if (quad == 0) {
        az[0] = (short)f2bf_bits(t4.x);
        az[1] = (short)f2bf_bits(t4.y);
        az[2] = (short)f2bf_bits(t4.z);
        az[3] = (short)f2bf_bits(t4.w);
      }
#pragma unroll
      for (int nt = 0; nt < 4; ++nt)
        acc1[nt] = __builtin_amdgcn_mfma_f32_16x16x32_bf16(az, bWa1[nt], acc1[nt], 0, 0, 0);
    } else {
      const ushort_t* tb = (const ushort_t*)tin;
      short8 a0 = *(const short8*)(tb + (size_t)(tile + col) * 64 + quad * 8);
      short8 a1 = *(const short8*)(tb + (size_t)(tile + col) * 64 + 32 + quad * 8);
#pragma unroll
      for (int nt = 0; nt < 4; ++nt) {
        acc1[nt] = __builtin_amdgcn_mfma_f32_16x16x32_bf16(a0, bWa[0][nt], acc1[nt], 0, 0, 0);
        acc1[nt] = __builtin_amdgcn_mfma_f32_16x16x32_bf16(a1, bWa[1][nt], acc1[nt], 0, 0, 0);
      }
    }

    // relu -> bf16 -> wave-private swizzled LDS (C-layout write, A-layout read)
#pragma unroll
    for (int nt = 0; nt < 4; ++nt) {
      int oblk = nt * 2 + (col >> 3);
#pragma unroll
      for (int r = 0; r < 4; ++r) {
        int row = quad * 4 + r;
        float z = fmaxf(acc1[nt][r] + ba_n[nt], 0.0f);
        zt[wbase + row * 64 + (((oblk ^ (row & 7)) << 3) | (col & 7))] = f2bf_bits(z);
      }
    }
    short8 az0 = *(const short8*)&zt[wbase + col * 64 + ((quad ^ (col & 7)) << 3)];
    short8 az1 = *(const short8*)&zt[wbase + col * 64 + (((4 + quad) ^ (col & 7)) << 3)];

    f32x4 acc2[4];
#pragma unroll
    for (int nt = 0; nt < 4; ++nt) acc2[nt] = (f32x4){0.f, 0.f, 0.f, 0.f};
#pragma unroll
    for (int nt = 0; nt < 4; ++nt) {
      acc2[nt] = __builtin_amdgcn_mfma_f32_16x16x32_bf16(az0, bWb[0][nt], acc2[nt], 0, 0, 0);
      acc2[nt] = __builtin_amdgcn_mfma_f32_16x16x32_bf16(az1, bWb[1][nt], acc2[nt], 0, 0, 0);
    }
#pragma unroll
    for (int nt = 0; nt < 4; ++nt) {
#pragma unroll
      for (int r = 0; r < 4; ++r) {
        int row = tile + quad * 4 + r;
        float v = fmaxf(acc2[nt][r] + bb_n[nt], 0.0f);
        if (BFOUT) routb[(size_t)row * 64 + nt * 16 + col] = f2bf_bits(v);
        else       routf[(size_t)row * 64 + nt * 16 + col] = v;
        scol[nt] += v; qcol[nt] += v * v;
      }
    }
  }

#pragma unroll
  for (int nt = 0; nt < 4; ++nt) {
    float s = scol[nt], q = qcol[nt];
    s += __shfl_xor(s, 16); s += __shfl_xor(s, 32);
    q += __shfl_xor(q, 16); q += __shfl_xor(q, 32);
    if (quad == 0) {
      red[wave * 128 + nt * 16 + col] = s;
      red[wave * 128 + 64 + nt * 16 + col] = q;
    }
  }
  __syncthreads();
  if (tid < 128)
    part[blockIdx.x * 128 + tid] =
        red[tid] + red[128 + tid] + red[256 + tid] + red[384 + tid];
}

// ---------------------------------------------------------------- BN finalize (2-stage)
__global__ __launch_bounds__(256) void reduce_part(
    const float* __restrict__ part, double* __restrict__ tot) {
  __shared__ double sh[256];
  const int c = blockIdx.x, tid = threadIdx.x;   // grid = 128
  double a = 0.0;
  for (int b = tid; b < NBLKM; b += 256) a += (double)part[b * 128 + c];
  sh[tid] = a;
  __syncthreads();
  for (int s = 128; s; s >>= 1) {
    if (tid < s) sh[tid] += sh[tid + s];
    __syncthreads();
  }
  if (tid == 0) tot[c] = sh[0];
}

__global__ __launch_bounds__(64) void finalize2(
    const double* __restrict__ tot, const float* __restrict__ gma,
    const float* __restrict__ bta, float* __restrict__ ss) {
  int c = threadIdx.x;
  double mean = tot[c] / (double)NN;
  double var = tot[64 + c] / (double)NN - mean * mean;
  double sc = (double)gma[c] / sqrt(var + 1e-5);
  ss[c] = (float)sc;
  ss[64 + c] = (float)((double)bta[c] - mean * sc);
}

// ---------------------------------------------------------------- pool + fc (fp32 L3 rows)
__global__ __launch_bounds__(64) void pool_fc(
    const float* __restrict__ r3, const float* __restrict__ ss,
    const float* __restrict__ wfc, const float* __restrict__ bfc,
    float* __restrict__ out) {
  int g = blockIdx.x, c = threadIdx.x;
  const float* base = r3 + (size_t)g * NPG * 64;
  float s = 0.f;
#pragma unroll
  for (int n = 0; n < NPG; ++n) s += base[n * 64 + c];
  float pooled = fmaf(ss[c], s, (float)NPG * ss[64 + c]);
#pragma unroll
  for (int j = 0; j < 3; ++j) {
    float v = pooled * wfc[c * 3 + j];
    for (int m = 32; m; m >>= 1) v += __shfl_xor(v, m);
    if (c == 0) out[g * 3 + j] = v + bfc[j];
  }
}

// ---------------------------------------------------------------- launch
extern "C" void kernel_launch(void* const* d_in, const int* in_sizes, int n_in,
                              void* d_out, int out_size, void* d_ws, size_t ws_size,
                              hipStream_t stream) {
  const float* x    = (const float*)d_in[0];
  const int*   srcE = (const int*)d_in[1];
  const int*   dstE = (const int*)d_in[2];
  const float* W1a = (const float*)d_in[4],  *b1a = (const float*)d_in[5];
  const float* W1b = (const float*)d_in[6],  *b1b = (const float*)d_in[7];
  const float* g1  = (const float*)d_in[8],  *be1 = (const float*)d_in[9];
  const float* W2a = (const float*)d_in[10], *b2a = (const float*)d_in[11];
  const float* W2b = (const float*)d_in[12], *b2b = (const float*)d_in[13];
  const float* g2  = (const float*)d_in[14], *be2 = (const float*)d_in[15];
  const float* W3a = (const float*)d_in[16], *b3a = (const float*)d_in[17];
  const float* W3b = (const float*)d_in[18], *b3b = (const float*)d_in[19];
  const float* g3  = (const float*)d_in[20], *be3 = (const float*)d_in[21];
  const float* Wfc = (const float*)d_in[22], *bfc = (const float*)d_in[23];

  float* ws = (float*)d_ws;
  ushort_t* Rb     = (ushort_t*)(ws + OFF_R);    // bf16 rows + sentinel (L1/L2 out)
  float*    Rf     = ws + OFF_R;                 // fp32 view (L3 out, H dead)
  void*     AGGBF  = (void*)(ws + OFF_AGGBF);    // gather output t
  uint2*    RECS   = (uint2*)(ws + OFF_AGGBF);   // alias: dead before gather1
  int*      CSR    = (int*)(ws + OFF_CSR);
  int*      CNT    = (int*)(ws + OFF_CNT);
  int*      OFFA   = (int*)(ws + OFF_OFFA);
  int*      BCUR   = (int*)(ws + OFF_BCUR);
  float*    PART   = ws + OFF_PART;
  double*   TOT    = (double*)(ws + OFF_TOT);
  ushort_t* WTB    = (ushort_t*)(ws + OFF_WTB);
  float*    SS     = ws + OFF_SS;

  prep_weights<<<6, 256, 0, stream>>>(W1a, W1b, W2a, W2b, W3a, W3b, WTB);

  hipMemsetAsync(BCUR, 0, 256 * sizeof(int), stream);
  hipMemsetAsync(Rb + (size_t)NN * 64, 0, 128, stream);   // sentinel zero row

  // ---- CSR build (bucket sort, LDS cursors, padded to 8 with sentinel NN)
  p3_bin<<<P3BLK, 256, 0, stream>>>(srcE, dstE, BCUR, RECS);
  p4_build<<<NB, 1024, 0, stream>>>(RECS, BCUR, CSR, CNT, OFFA);

  // ---- layer 1: gather(x) -> AGGBF(fp32 t), MLP -> Rb(bf16)
  gather1<<<NN / 256, 256, 0, stream>>>((const float4*)x, CSR, OFFA, CNT,
                                        (float4*)AGGBF);
  mlp_mfma<true, true><<<NBLKM, 256, 0, stream>>>(AGGBF, WTB + WB_W1A, b1a,
                                                  WTB + WB_W1B, b1b,
                                                  nullptr, Rb, PART);
  reduce_part<<<128, 256, 0, stream>>>(PART, TOT);
  finalize2<<<1, 64, 0, stream>>>(TOT, g1, be1, SS + 0);

  // ---- layer 2: gather(Rb) -> AGGBF(bf16 t), MLP -> Rb
  gather64v2<<<NN / 4, 256, 0, stream>>>(Rb, CSR, OFFA, CNT, SS + 0,
                                         (ushort_t*)AGGBF);
  mlp_mfma<false, true><<<NBLKM, 256, 0, stream>>>(AGGBF, WTB + WB_W2A, b2a,
                                                   WTB + WB_W2B, b2b,
                                                   nullptr, Rb, PART);
  reduce_part<<<128, 256, 0, stream>>>(PART, TOT);
  finalize2<<<1, 64, 0, stream>>>(TOT, g2, be2, SS + 128);

  // ---- layer 3: gather(Rb) -> AGGBF, MLP -> Rf (fp32, overwrites dead Rb)
  gather64v2<<<NN / 4, 256, 0, stream>>>(Rb, CSR, OFFA, CNT, SS + 128,
                                         (ushort_t*)AGGBF);
  mlp_mfma<false, false><<<NBLKM, 256, 0, stream>>>(AGGBF, WTB + WB_W3A, b3a,
                                                    WTB + WB_W3B, b3b,
                                                    Rf, nullptr, PART);
  reduce_part<<<128, 256, 0, stream>>>(PART, TOT);
  finalize2<<<1, 64, 0, stream>>>(TOT, g3, be3, SS + 256);

  // ---- pool + classifier
  pool_fc<<<NG, 64, 0, stream>>>(Rf, SS + 256, Wfc, bfc, (float*)d_out);
}

// Round 13
// 780.473 us; speedup vs baseline: 1.0248x; 1.0248x over previous
//
#include <hip/hip_runtime.h>
#include <hip/hip_bf16.h>

// Problem constants (fixed by the reference)
#define NN   507904          // nodes = 8192*62
#define NE   4063232         // edges = NN*8
#define NG   8192            // graphs
#define NPG  62              // nodes per graph
#define NBLKM 992            // NN/512 (mlp grid; 512 rows/block, 8 iters)

// Bucket sort parameters
#define NB    248            // buckets = NN/2048 (exact)
#define BRNG  2048           // nodes per bucket (bucket = dst>>11)
#define BCAP  17152          // bucket record capacity (mean 16384, +6 sigma)
#define PBCAP 31744          // padded csr capacity/bucket (8-aligned)
#define P3BLK 992            // NE/4096 (exact)
#define CSRSZ (NB * PBCAP)   // 7,872,512 ints

// ---------------------------------------------------------------- ws layout (4B units)
#define OFF_R     0                          // NN*64 units; bf16 rows (+sentinel) or fp32 L3 out
#define OFF_AGGBF (OFF_R + NN * 64)          // t: bf16 NN*64 | aliased: RECS / T1
#define OFF_CSR   (OFF_AGGBF + NN * 32)      // CSRSZ ints (padded CSR)
#define OFF_CNT   (OFF_CSR + CSRSZ)          // NN ints
#define OFF_OFFA  (OFF_CNT + NN)             // NN ints
#define OFF_BCUR  (OFF_OFFA + NN)            // 256 ints
#define OFF_PART  (OFF_BCUR + 256)           // NBLKM*128 floats
#define OFF_WTB   (OFF_PART + NBLKM * 128)   // bf16 weights: 22528 ushort = 11264 units
#define OFF_SS    (OFF_WTB + 11264)          // 3 x (scale[64], shift[64])

// bf16 weight offsets (ushort units)
#define WB_W1B 0
#define WB_W2A 4096
#define WB_W2B 8192
#define WB_W3A 12288
#define WB_W3B 16384
#define WB_W1A 20480         // 64 x 32, zero-padded K (only k<4 nonzero)

typedef __attribute__((ext_vector_type(8))) short short8;
typedef __attribute__((ext_vector_type(4))) float f32x4;
typedef unsigned short ushort_t;

__device__ __forceinline__ ushort_t f2bf_bits(float f) {
  union { float f; unsigned u; } x; x.f = f;
  unsigned r = x.u + 0x7FFF + ((x.u >> 16) & 1);
  return (ushort_t)(r >> 16);
}
__device__ __forceinline__ float bf_lo(unsigned u) {
  union { unsigned i; float f; } x; x.i = u << 16; return x.f;
}
__device__ __forceinline__ float bf_hi(unsigned u) {
  union { unsigned i; float f; } x; x.i = u & 0xFFFF0000u; return x.f;
}

// ---------------------------------------------------------------- weight prep (+ zero-init)
__global__ __launch_bounds__(256) void prep_weights(
    const float* __restrict__ w1a, const float* __restrict__ w1b,
    const float* __restrict__ w2a, const float* __restrict__ w2b,
    const float* __restrict__ w3a, const float* __restrict__ w3b,
    ushort_t* __restrict__ wtb, int* __restrict__ bcur,
    unsigned* __restrict__ sentinel) {
  int b = blockIdx.x, tid = threadIdx.x;
  if (b == 0) {
    // W1a [4][64] -> bf16 [n][32], zero-padded K (k<4 nonzero)
    ushort_t* d = wtb + WB_W1A;
    for (int i = tid; i < 2048; i += 256) {
      int n = i >> 5, k = i & 31;
      d[i] = (k < 4) ? f2bf_bits(w1a[k * 64 + n]) : (ushort_t)0;
    }
  } else if (b == 6) {
    bcur[tid] = 0;                       // 256 ints
    if (tid < 32) sentinel[tid] = 0;     // sentinel row: 128 B
  } else {
    const float* s; ushort_t* d;
    switch (b) {
      case 1: s = w1b; d = wtb + WB_W1B; break;
      case 2: s = w2a; d = wtb + WB_W2A; break;
      case 3: s = w2b; d = wtb + WB_W2B; break;
      case 4: s = w3a; d = wtb + WB_W3A; break;
      default: s = w3b; d = wtb + WB_W3B; break;
    }
    for (int i = tid; i < 4096; i += 256) {
      int k = i >> 6, n = i & 63;              // src [k][n]
      d[n * 64 + k] = f2bf_bits(s[i]);         // dst [n][k]
    }
  }
}

// ---------------------------------------------------------------- CSR build: phase 1 (R6-proven)
__global__ __launch_bounds__(256) void p3_bin(
    const int* __restrict__ src, const int* __restrict__ dst,
    int* __restrict__ bcur, uint2* __restrict__ recs) {
  __shared__ int histo[256];
  __shared__ int scan_s[256];
  __shared__ int base_s[256];
  __shared__ int cur_s[256];
  __shared__ uint2 buf[4096];
  const int tid = threadIdx.x;
  const int e0 = blockIdx.x * 4096;

  histo[tid] = 0;
  __syncthreads();

  int d_[16], s_[16];
#pragma unroll
  for (int k = 0; k < 16; ++k) {
    int e = e0 + k * 256 + tid;
    d_[k] = dst[e]; s_[k] = src[e];
    atomicAdd(&histo[d_[k] >> 11], 1);
  }
  __syncthreads();

  int v = histo[tid];
  scan_s[tid] = v; __syncthreads();
  for (int s = 1; s < 256; s <<= 1) {
    int add = (tid >= s) ? scan_s[tid - s] : 0;
    __syncthreads();
    scan_s[tid] += add;
    __syncthreads();
  }
  int excl = scan_s[tid] - v;
  if (tid < NB) base_s[tid] = atomicAdd(&bcur[tid], v);
  cur_s[tid] = excl;
  histo[tid] = excl;
  __syncthreads();

#pragma unroll
  for (int k = 0; k < 16; ++k) {
    int b = d_[k] >> 11;
    int p = atomicAdd(&cur_s[b], 1);
    uint2 r; r.x = (unsigned)d_[k]; r.y = (unsigned)s_[k];
    buf[p] = r;
  }
  __syncthreads();

  for (int i = tid; i < 4096; i += 256) {
    uint2 r = buf[i];
    int b = (int)(r.x >> 11);
    int g = base_s[b] + (i - histo[b]);
    if (g < BCAP) recs[(size_t)b * BCAP + g] = r;
  }
}

// ---------------------------------------------------------------- CSR build: phase 2 (R6-proven, LDS cursors)
__global__ __launch_bounds__(1024) void p4_build(
    const uint2* __restrict__ recs, const int* __restrict__ bcur,
    int* __restrict__ csr, int* __restrict__ cnt, int* __restrict__ offa) {
  __shared__ int lcnt[2048];
  __shared__ int pscan[1024];
  __shared__ int sstart[2048];
  __shared__ int scur[2048];
  const int b = blockIdx.x, tid = threadIdx.x;
  int m = bcur[b]; if (m > BCAP) m = BCAP;
  const int cbase = b * PBCAP;
  const int nbase = b << 11;
  const uint2* rp = recs + (size_t)b * BCAP;

  lcnt[tid] = 0; lcnt[1024 + tid] = 0;
  __syncthreads();
  for (int i = tid; i < m; i += 1024)
    atomicAdd(&lcnt[rp[i].x & (BRNG - 1)], 1);
  __syncthreads();

  int a0 = lcnt[2 * tid], a1 = lcnt[2 * tid + 1];
  int p0 = (a0 + 7) & ~7, p1 = (a1 + 7) & ~7;
  int ps = p0 + p1;
  pscan[tid] = ps; __syncthreads();
  for (int s = 1; s < 1024; s <<= 1) {
    int add = (tid >= s) ? pscan[tid - s] : 0;
    __syncthreads();
    pscan[tid] += add;
    __syncthreads();
  }
  int e0 = pscan[tid] - ps;
  sstart[2 * tid] = e0;          scur[2 * tid] = e0;
  sstart[2 * tid + 1] = e0 + p0; scur[2 * tid + 1] = e0 + p0;
  __syncthreads();

  cnt[nbase + tid] = lcnt[tid];
  cnt[nbase + 1024 + tid] = lcnt[1024 + tid];
  offa[nbase + tid] = cbase + sstart[tid];
  offa[nbase + 1024 + tid] = cbase + sstart[1024 + tid];
  __syncthreads();

  for (int i = tid; i < m; i += 1024) {
    uint2 r = rp[i];
    int p = atomicAdd(&scur[r.x & (BRNG - 1)], 1);
    csr[cbase + p] = (int)r.y;
  }
  __syncthreads();

#pragma unroll
  for (int k = 0; k < 2; ++k) {
    int i = k * 1024 + tid;
    int st = sstart[i], d = lcnt[i], p = (d + 7) & ~7;
    for (int q = d; q < p; ++q) csr[cbase + st + q] = NN;   // sentinel
  }
}

// ---------------------------------------------------------------- gather L1 (C=4)
__global__ __launch_bounds__(256) void gather1(
    const float4* __restrict__ x, const int* __restrict__ csr,
    const int* __restrict__ offa, const int* __restrict__ cnt,
    float4* __restrict__ tout) {
  int n = blockIdx.x * 256 + threadIdx.x;
  float4 a = x[n];
  int off = offa[n], deg = cnt[n];
  const int* cp = csr + off;
  int j = 0;
  for (; j + 4 <= deg; j += 4) {
    int s0 = cp[j], s1 = cp[j + 1], s2 = cp[j + 2], s3 = cp[j + 3];
    float4 v0 = x[s0], v1 = x[s1], v2 = x[s2], v3 = x[s3];
    a.x += v0.x + v1.x + v2.x + v3.x;
    a.y += v0.y + v1.y + v2.y + v3.y;
    a.z += v0.z + v1.z + v2.z + v3.z;
    a.w += v0.w + v1.w + v2.w + v3.w;
  }
  for (; j < deg; ++j) {
    float4 v = x[cp[j]];
    a.x += v.x; a.y += v.y; a.z += v.z; a.w += v.w;
  }
  tout[n] = a;
}

// ---------------------------------------------------------------- gather L2/3 (C=64, bf16 rows)
__global__ __launch_bounds__(256) void gather64v2(
    const ushort_t* __restrict__ h, const int* __restrict__ csr,
    const int* __restrict__ offa, const int* __restrict__ cnt,
    const float* __restrict__ ss, ushort_t* __restrict__ tout) {
  const int lane = threadIdx.x & 63;
  const int n = blockIdx.x * 4 + (threadIdx.x >> 6);
  const int g = lane >> 3, sub = lane & 7;
  const int deg = cnt[n];
  const int off = offa[n];
  const int chunks = (deg + 7) >> 3;

  float acc[8] = {0.f, 0.f, 0.f, 0.f, 0.f, 0.f, 0.f, 0.f};
  for (int c = 0; c < chunks; ++c) {
    int row = csr[off + (c << 3) + g];
    uint4 u = *(const uint4*)(h + (size_t)row * 64 + (sub << 3));
    acc[0] += bf_lo(u.x); acc[1] += bf_hi(u.x);
    acc[2] += bf_lo(u.y); acc[3] += bf_hi(u.y);
    acc[4] += bf_lo(u.z); acc[5] += bf_hi(u.z);
    acc[6] += bf_lo(u.w); acc[7] += bf_hi(u.w);
  }
#pragma unroll
  for (int j = 0; j < 8; ++j) {
    acc[j] += __shfl_xor(acc[j], 8);
    acc[j] += __shfl_xor(acc[j], 16);
    acc[j] += __shfl_xor(acc[j], 32);
  }

  if (g == 0) {
    uint4 u = *(const uint4*)(h + (size_t)n * 64 + (sub << 3));
    acc[0] += bf_lo(u.x); acc[1] += bf_hi(u.x);
    acc[2] += bf_lo(u.y); acc[3] += bf_hi(u.y);
    acc[4] += bf_lo(u.z); acc[5] += bf_hi(u.z);
    acc[6] += bf_lo(u.w); acc[7] += bf_hi(u.w);
    const float m1 = (float)(deg + 1);
    const float4* scp = (const float4*)(ss + (sub << 3));
    const float4* sfp = (const float4*)(ss + 64 + (sub << 3));
    float4 sc0 = scp[0], sc1 = scp[1];
    float4 sf0 = sfp[0], sf1 = sfp[1];
    float t0 = fmaf(sc0.x, acc[0], m1 * sf0.x);
    float t1 = fmaf(sc0.y, acc[1], m1 * sf0.y);
    float t2 = fmaf(sc0.z, acc[2], m1 * sf0.z);
    float t3 = fmaf(sc0.w, acc[3], m1 * sf0.w);
    float t4 = fmaf(sc1.x, acc[4], m1 * sf1.x);
    float t5 = fmaf(sc1.y, acc[5], m1 * sf1.y);
    float t6 = fmaf(sc1.z, acc[6], m1 * sf1.z);
    float t7 = fmaf(sc1.w, acc[7], m1 * sf1.w);
    uint4 o;
    o.x = ((unsigned)f2bf_bits(t1) << 16) | f2bf_bits(t0);
    o.y = ((unsigned)f2bf_bits(t3) << 16) | f2bf_bits(t2);
    o.z = ((unsigned)f2bf_bits(t5) << 16) | f2bf_bits(t4);
    o.w = ((unsigned)f2bf_bits(t7) << 16) | f2bf_bits(t6);
    *(uint4*)(tout + (size_t)n * 64 + (sub << 3)) = o;
  }
}

// ---------------------------------------------------------------- MFMA MLP (unified L1/L2/L3)
// 512 rows/block, 8 iters; grid 992 (R11-proven).
template <bool L1, bool BFOUT>
__global__ __launch_bounds__(256) void mlp_mfma(
    const void* __restrict__ tin,
    const ushort_t* __restrict__ WaTb,   // L1: bf16 [n][32] padded; else [n][64]
    const float* __restrict__ ba,
    const ushort_t* __restrict__ WbTb,   // bf16 [n][64]
    const float* __restrict__ bb,
    float* __restrict__ routf, ushort_t* __restrict__ routb,
    float* __restrict__ part) {
  __shared__ __align__(16) ushort_t zt[4096];
  __shared__ float red[512];
  const int tid = threadIdx.x;
  const int wave = tid >> 6, lane = tid & 63;
  const int col = lane & 15, quad = lane >> 4;

  short8 bWa1[4];        // L1 only
  short8 bWa[2][4];      // !L1 only
  short8 bWb[2][4];
#pragma unroll
  for (int nt = 0; nt < 4; ++nt) {
    if (L1) {
      bWa1[nt] = *(const short8*)(WaTb + (nt * 16 + col) * 32 + quad * 8);
    } else {
#pragma unroll
      for (int k0 = 0; k0 < 2; ++k0)
        bWa[k0][nt] = *(const short8*)(WaTb + (nt * 16 + col) * 64 + k0 * 32 + quad * 8);
    }
#pragma unroll
    for (int k0 = 0; k0 < 2; ++k0)
      bWb[k0][nt] = *(const short8*)(WbTb + (nt * 16 + col) * 64 + k0 * 32 + quad * 8);
  }
  float ba_n[4], bb_n[4];
#pragma unroll
  for (int nt = 0; nt < 4; ++nt) {
    ba_n[nt] = ba[nt * 16 + col];
    bb_n[nt] = bb[nt * 16 + col];
  }

  const int wbase = wave * 1024;
  float scol[4] = {0, 0, 0, 0}, qcol[4] = {0, 0, 0, 0};

  for (int it = 0; it < 8; ++it) {
    const int tile = blockIdx.x * 512 + it * 64 + wave * 16;

    f32x4 acc1[4];
#pragma unroll
    for (int nt = 0; nt < 4; ++nt) acc1[nt] = (f32x4){0.f, 0.f, 0.f, 0.f};

    if constexpr (L1) {
      // A-frag: m=col, k=quad*8+j; real data only k<4
      float4 t4 = ((const float4*)tin)[tile + col];
      short8 az = {0, 0, 0, 0, 0, 0, 0, 0};
      if (quad == 0) {
        az[0] = (short)f2bf_bits(t4.x);
        az[1] = (short)f2bf_bits(t4.y);
        az[2] = (short)f2bf_bits(t4.z);
        az[3] = (short)f2bf_bits(t4.w);
      }
#pragma unroll
      for (int nt = 0; nt < 4; ++nt)
        acc1[nt] = __builtin_amdgcn_mfma_f32_16x16x32_bf16(az, bWa1[nt], acc1[nt], 0, 0, 0);
    } else {
      const ushort_t* tb = (const ushort_t*)tin;
      short8 a0 = *(const short8*)(tb + (size_t)(tile + col) * 64 + quad * 8);
      short8 a1 = *(const short8*)(tb + (size_t)(tile + col) * 64 + 32 + quad * 8);
#pragma unroll
      for (int nt = 0; nt < 4; ++nt) {
        acc1[nt] = __builtin_amdgcn_mfma_f32_16x16x32_bf16(a0, bWa[0][nt], acc1[nt], 0, 0, 0);
        acc1[nt] = __builtin_amdgcn_mfma_f32_16x16x32_bf16(a1, bWa[1][nt], acc1[nt], 0, 0, 0);
      }
    }

    // relu -> bf16 -> wave-private swizzled LDS (C-layout write, A-layout read)
#pragma unroll
    for (int nt = 0; nt < 4; ++nt) {
      int oblk = nt * 2 + (col >> 3);
#pragma unroll
      for (int r = 0; r < 4; ++r) {
        int row = quad * 4 + r;
        float z = fmaxf(acc1[nt][r] + ba_n[nt], 0.0f);
        zt[wbase + row * 64 + (((oblk ^ (row & 7)) << 3) | (col & 7))] = f2bf_bits(z);
      }
    }
    short8 az0 = *(const short8*)&zt[wbase + col * 64 + ((quad ^ (col & 7)) << 3)];
    short8 az1 = *(const short8*)&zt[wbase + col * 64 + (((4 + quad) ^ (col & 7)) << 3)];

    f32x4 acc2[4];
#pragma unroll
    for (int nt = 0; nt < 4; ++nt) acc2[nt] = (f32x4){0.f, 0.f, 0.f, 0.f};
#pragma unroll
    for (int nt = 0; nt < 4; ++nt) {
      acc2[nt] = __builtin_amdgcn_mfma_f32_16x16x32_bf16(az0, bWb[0][nt], acc2[nt], 0, 0, 0);
      acc2[nt] = __builtin_amdgcn_mfma_f32_16x16x32_bf16(az1, bWb[1][nt], acc2[nt], 0, 0, 0);
    }
#pragma unroll
    for (int nt = 0; nt < 4; ++nt) {
#pragma unroll
      for (int r = 0; r < 4; ++r) {
        int row = tile + quad * 4 + r;
        float v = fmaxf(acc2[nt][r] + bb_n[nt], 0.0f);
        if (BFOUT) routb[(size_t)row * 64 + nt * 16 + col] = f2bf_bits(v);
        else       routf[(size_t)row * 64 + nt * 16 + col] = v;
        scol[nt] += v; qcol[nt] += v * v;
      }
    }
  }

#pragma unroll
  for (int nt = 0; nt < 4; ++nt) {
    float s = scol[nt], q = qcol[nt];
    s += __shfl_xor(s, 16); s += __shfl_xor(s, 32);
    q += __shfl_xor(q, 16); q += __shfl_xor(q, 32);
    if (quad == 0) {
      red[wave * 128 + nt * 16 + col] = s;
      red[wave * 128 + 64 + nt * 16 + col] = q;
    }
  }
  __syncthreads();
  if (tid < 128)
    part[blockIdx.x * 128 + tid] =
        red[tid] + red[128 + tid] + red[256 + tid] + red[384 + tid];
}

// ---------------------------------------------------------------- BN reduce+finalize (merged)
// grid = 64; block c reduces sum (col c) and sumsq (col 64+c), writes ss.
__global__ __launch_bounds__(256) void reduce_finalize(
    const float* __restrict__ part, const float* __restrict__ gma,
    const float* __restrict__ bta, float* __restrict__ ss) {
  __shared__ double sh[512];
  const int c = blockIdx.x, tid = threadIdx.x;
  double a = 0.0, b = 0.0;
  for (int blk = tid; blk < NBLKM; blk += 256) {
    a += (double)part[blk * 128 + c];
    b += (double)part[blk * 128 + 64 + c];
  }
  sh[tid] = a; sh[256 + tid] = b;
  __syncthreads();
  for (int s = 128; s; s >>= 1) {
    if (tid < s) { sh[tid] += sh[tid + s]; sh[256 + tid] += sh[256 + tid + s]; }
    __syncthreads();
  }
  if (tid == 0) {
    double mean = sh[0] / (double)NN;
    double var = sh[256] / (double)NN - mean * mean;
    double sc = (double)gma[c] / sqrt(var + 1e-5);
    ss[c] = (float)sc;
    ss[64 + c] = (float)((double)bta[c] - mean * sc);
  }
}

// ---------------------------------------------------------------- pool + fc (fp32 L3 rows)
__global__ __launch_bounds__(64) void pool_fc(
    const float* __restrict__ r3, const float* __restrict__ ss,
    const float* __restrict__ wfc, const float* __restrict__ bfc,
    float* __restrict__ out) {
  int g = blockIdx.x, c = threadIdx.x;
  const float* base = r3 + (size_t)g * NPG * 64;
  float s = 0.f;
#pragma unroll
  for (int n = 0; n < NPG; ++n) s += base[n * 64 + c];
  float pooled = fmaf(ss[c], s, (float)NPG * ss[64 + c]);
#pragma unroll
  for (int j = 0; j < 3; ++j) {
    float v = pooled * wfc[c * 3 + j];
    for (int m = 32; m; m >>= 1) v += __shfl_xor(v, m);
    if (c == 0) out[g * 3 + j] = v + bfc[j];
  }
}

// ---------------------------------------------------------------- launch
extern "C" void kernel_launch(void* const* d_in, const int* in_sizes, int n_in,
                              void* d_out, int out_size, void* d_ws, size_t ws_size,
                              hipStream_t stream) {
  const float* x    = (const float*)d_in[0];
  const int*   srcE = (const int*)d_in[1];
  const int*   dstE = (const int*)d_in[2];
  const float* W1a = (const float*)d_in[4],  *b1a = (const float*)d_in[5];
  const float* W1b = (const float*)d_in[6],  *b1b = (const float*)d_in[7];
  const float* g1  = (const float*)d_in[8],  *be1 = (const float*)d_in[9];
  const float* W2a = (const float*)d_in[10], *b2a = (const float*)d_in[11];
  const float* W2b = (const float*)d_in[12], *b2b = (const float*)d_in[13];
  const float* g2  = (const float*)d_in[14], *be2 = (const float*)d_in[15];
  const float* W3a = (const float*)d_in[16], *b3a = (const float*)d_in[17];
  const float* W3b = (const float*)d_in[18], *b3b = (const float*)d_in[19];
  const float* g3  = (const float*)d_in[20], *be3 = (const float*)d_in[21];
  const float* Wfc = (const float*)d_in[22], *bfc = (const float*)d_in[23];

  float* ws = (float*)d_ws;
  ushort_t* Rb     = (ushort_t*)(ws + OFF_R);    // bf16 rows + sentinel (L1/L2 out)
  float*    Rf     = ws + OFF_R;                 // fp32 view (L3 out, Rb dead)
  void*     AGGBF  = (void*)(ws + OFF_AGGBF);    // gather output t
  uint2*    RECS   = (uint2*)(ws + OFF_AGGBF);   // alias: dead before gather1
  int*      CSR    = (int*)(ws + OFF_CSR);
  int*      CNT    = (int*)(ws + OFF_CNT);
  int*      OFFA   = (int*)(ws + OFF_OFFA);
  int*      BCUR   = (int*)(ws + OFF_BCUR);
  float*    PART   = ws + OFF_PART;
  ushort_t* WTB    = (ushort_t*)(ws + OFF_WTB);
  float*    SS     = ws + OFF_SS;

  // weights + BCUR/sentinel zero-init in one dispatch
  prep_weights<<<7, 256, 0, stream>>>(W1a, W1b, W2a, W2b, W3a, W3b, WTB, BCUR,
                                      (unsigned*)(Rb + (size_t)NN * 64));

  // ---- CSR build (bucket sort, LDS cursors, padded to 8 with sentinel NN)
  p3_bin<<<P3BLK, 256, 0, stream>>>(srcE, dstE, BCUR, RECS);
  p4_build<<<NB, 1024, 0, stream>>>(RECS, BCUR, CSR, CNT, OFFA);

  // ---- layer 1: gather(x) -> AGGBF(fp32 t), MLP -> Rb(bf16)
  gather1<<<NN / 256, 256, 0, stream>>>((const float4*)x, CSR, OFFA, CNT,
                                        (float4*)AGGBF);
  mlp_mfma<true, true><<<NBLKM, 256, 0, stream>>>(AGGBF, WTB + WB_W1A, b1a,
                                                  WTB + WB_W1B, b1b,
                                                  nullptr, Rb, PART);
  reduce_finalize<<<64, 256, 0, stream>>>(PART, g1, be1, SS + 0);

  // ---- layer 2: gather(Rb) -> AGGBF(bf16 t), MLP -> Rb
  gather64v2<<<NN / 4, 256, 0, stream>>>(Rb, CSR, OFFA, CNT, SS + 0,
                                         (ushort_t*)AGGBF);
  mlp_mfma<false, true><<<NBLKM, 256, 0, stream>>>(AGGBF, WTB + WB_W2A, b2a,
                                                   WTB + WB_W2B, b2b,
                                                   nullptr, Rb, PART);
  reduce_finalize<<<64, 256, 0, stream>>>(PART, g2, be2, SS + 128);

  // ---- layer 3: gather(Rb) -> AGGBF, MLP -> Rf (fp32, overwrites dead Rb)
  gather64v2<<<NN / 4, 256, 0, stream>>>(Rb, CSR, OFFA, CNT, SS + 128,
                                         (ushort_t*)AGGBF);
  mlp_mfma<false, false><<<NBLKM, 256, 0, stream>>>(AGGBF, WTB + WB_W3A, b3a,
                                                    WTB + WB_W3B, b3b,
                                                    Rf, nullptr, PART);
  reduce_finalize<<<64, 256, 0, stream>>>(PART, g3, be3, SS + 256);

  // ---- pool + classifier
  pool_fc<<<NG, 64, 0, stream>>>(Rf, SS + 256, Wfc, bfc, (float*)d_out);
}